// Round 5
// baseline (2262.840 us; speedup 1.0000x reference)
//
#include <hip/hip_runtime.h>

// Elman RNN on MI355X. B=64, T=2048, D=H=256.
// Key trick this round: SWAPPED MFMA operands (acc = mfma(W_frag, h_frag)):
// computes the transposed tile so each lane holds (batch-row m, 4 consecutive
// cols 4q+r). h-writes to LDS become packed ds_write_b64 (was 8x scattered
// b16), px loads / ys stores become b128 (was 8x b32). A-fragment reads and
// swizzle unchanged.
// Kernel 1: px = xs @ W_ih + b_hh (f16 MFMA, fp32 out) into ys region.
// Kernel 2: scan, 4 blocks x 16 rows, 8 waves x 32 cols, 2 waves/SIMD.
//           Buffer ops (SRSRC + voffset + soffset=t<<10), LDS-only barrier.

typedef _Float16 half8 __attribute__((ext_vector_type(8)));
typedef _Float16 half4 __attribute__((ext_vector_type(4)));
typedef float floatx4 __attribute__((ext_vector_type(4)));
typedef float f32x4 __attribute__((ext_vector_type(4)));
typedef int int4v __attribute__((ext_vector_type(4)));

constexpr int Bb = 64, Tt = 2048, Dd = 256, Hh = 256;

// LDS address for h[row][col], row in [0,16), col in [0,256), f16 elements.
// 16B blocks along col; XOR-swizzle block index with (row&7): A-fragment
// ds_read_b128 (fixed col-block per lane, row=lane&15) is conflict-free.
__device__ __forceinline__ int lds_addr(int row, int col) {
    return row * 512 + ((((col >> 3) ^ (row & 7)) & 31) << 4) + ((col & 7) << 1);
}

__device__ __forceinline__ float fast_tanh(float x) {
    // tanh(x) = 1 - 2/(exp2(x*2*log2(e)) + 1); exact at +/-inf, ~1e-6 abs err.
    float e = __builtin_amdgcn_exp2f(x * 2.885390081777927f);
    float r = __builtin_amdgcn_rcpf(e + 1.0f);
    return __builtin_fmaf(-2.0f, r, 1.0f);
}

// Raw buffer descriptor (stride=0 -> num_records in bytes; raw dword word3).
__device__ __forceinline__ __amdgpu_buffer_rsrc_t mkrsrc(void* p, unsigned bytes) {
    return __builtin_amdgcn_make_buffer_rsrc(p, (short)0, (int)bytes, 0x00020000);
}

__device__ __forceinline__ floatx4 buf_load_f32x4(__amdgpu_buffer_rsrc_t rs, int voff, int soff) {
    int4v v = __builtin_amdgcn_raw_buffer_load_b128(rs, voff, soff, 0);
    return __builtin_bit_cast(floatx4, v);
}

__device__ __forceinline__ void buf_store_f32x4(floatx4 v, __amdgpu_buffer_rsrc_t rs, int voff, int soff) {
    __builtin_amdgcn_raw_buffer_store_b128(__builtin_bit_cast(int4v, v), rs, voff, soff, 0);
}

// LDS-only barrier: completes this wave's ds ops, then syncs. Does NOT drain
// vmcnt, so buffer loads/stores stay in flight across steps.
#define LDS_BARRIER() asm volatile("s_waitcnt lgkmcnt(0)\n\ts_barrier" ::: "memory")

// ---------------------------------------------------------------------------
// Kernel 1: px[b*T+t][n] = sum_k xs[b*T+t][k] * W_ih[k][n] + b_hh[n]
// Swapped-operand MFMA: lane holds (xs-row m, cols 64w+16tt+4q..+3) -> 4x b128
// stores per row-tile (was 16x b32).
// ---------------------------------------------------------------------------
__global__ __launch_bounds__(256, 2) void px_gemm(const float* __restrict__ xs,
                                                  const float* __restrict__ Wih,
                                                  const float* __restrict__ bhh,
                                                  float* __restrict__ px) {
    const int lane = threadIdx.x & 63;
    const int w = threadIdx.x >> 6;   // 0..3
    const int q = lane >> 4;          // 0..3
    const int m = lane & 15;

    // W_ih fragments: lane (q,m) holds W[k=8q+j+32c][64w+16tt+m].
    half8 bf[4][8];
#pragma unroll
    for (int tt = 0; tt < 4; ++tt) {
        const int n = 64 * w + 16 * tt + m;
#pragma unroll
        for (int c = 0; c < 8; ++c) {
            half8 f;
#pragma unroll
            for (int j = 0; j < 8; ++j)
                f[j] = (_Float16)Wih[(32 * c + 8 * q + j) * Hh + n];
            bf[tt][c] = f;
        }
    }
    // Bias for the transposed output: cols 64w+16tt+4q..+3 (per-lane via q).
    f32x4 bias2[4];
#pragma unroll
    for (int tt = 0; tt < 4; ++tt)
        bias2[tt] = *(const f32x4*)(bhh + 64 * w + 16 * tt + 4 * q);

    for (int i = 0; i < 8; ++i) {
        const int tau = blockIdx.x * 8 + i;             // 16-row tile index
        const float* arow = xs + (size_t)(tau * 16 + m) * Dd;
        half8 af[8];
#pragma unroll
        for (int c = 0; c < 8; ++c) {
            f32x4 lo = *(const f32x4*)(arow + 32 * c + 8 * q);
            f32x4 hi = *(const f32x4*)(arow + 32 * c + 8 * q + 4);
            half8 f;
            f[0] = (_Float16)lo[0]; f[1] = (_Float16)lo[1];
            f[2] = (_Float16)lo[2]; f[3] = (_Float16)lo[3];
            f[4] = (_Float16)hi[0]; f[5] = (_Float16)hi[1];
            f[6] = (_Float16)hi[2]; f[7] = (_Float16)hi[3];
            af[c] = f;
        }
        floatx4 acc[4];
#pragma unroll
        for (int tt = 0; tt < 4; ++tt) {
            acc[tt][0] = bias2[tt][0]; acc[tt][1] = bias2[tt][1];
            acc[tt][2] = bias2[tt][2]; acc[tt][3] = bias2[tt][3];
        }
        // Swapped operands: D[wih-col][xs-row] -> lane (q,m): row m, cols 4q+r.
#pragma unroll
        for (int c = 0; c < 8; ++c)
#pragma unroll
            for (int tt = 0; tt < 4; ++tt)
                acc[tt] = __builtin_amdgcn_mfma_f32_16x16x32_f16(bf[tt][c], af[c], acc[tt], 0, 0, 0);
#pragma unroll
        for (int tt = 0; tt < 4; ++tt)
            *(f32x4*)(px + (size_t)(tau * 16 + m) * Hh + 64 * w + 16 * tt + 4 * q) =
                *(f32x4*)&acc[tt];
    }
}

// ---------------------------------------------------------------------------
// Kernel 2: scan. Grid = 4 blocks (16 batch rows each), 512 thr = 8 waves
// (2 waves/SIMD). Wave w owns cols [32w, 32w+32); W_hh fragments in 64 VGPRs.
// Per step: 8x ds_read_b128 A frags, 2x b128 px prefetch (rides across the
// barrier), 16 MFMA swapped (lane -> row m, cols 4q+r), tanh, 2x b128 ys
// store + 2x ds_write_b64 packed h, LDS-only barrier.
// ---------------------------------------------------------------------------
__global__ __launch_bounds__(512, 2) void rnn_scan(const float* __restrict__ c0,
                                                   const float* __restrict__ Whh,
                                                   float* __restrict__ hfin,
                                                   float* __restrict__ ys) {
    __shared__ alignas(16) unsigned char hb[2][8192];
    const int g = blockIdx.x;         // row group: rows [16g, 16g+16)
    const int lane = threadIdx.x & 63;
    const int w = threadIdx.x >> 6;   // 0..7
    const int q = lane >> 4;
    const int m = lane & 15;

    // Buffer descriptors (uniform -> SGPRs). OOB loads return 0 (t=T prefetch).
    const __amdgpu_buffer_rsrc_t rsYS = mkrsrc(ys, (unsigned)Bb * Tt * Hh * 4u);
    const __amdgpu_buffer_rsrc_t rsHF = mkrsrc(hfin, (unsigned)Bb * Hh * 4u);

    // W_hh fragments: lane (q,m) holds W[k=8q+j+32c][32w+16tt+m]. 64 VGPRs.
    half8 bf[2][8];
#pragma unroll
    for (int tt = 0; tt < 2; ++tt) {
        const int n = 32 * w + 16 * tt + m;
#pragma unroll
        for (int c = 0; c < 8; ++c) {
            half8 f;
#pragma unroll
            for (int j = 0; j < 8; ++j)
                f[j] = (_Float16)Whh[(32 * c + 8 * q + j) * Hh + n];
            bf[tt][c] = f;
        }
    }

    // h_0 = c rows -> LDS buffer 0 (f16, swizzled).
    for (int i = threadIdx.x; i < 16 * 256; i += 512) {
        const int row = i >> 8, col = i & 255;
        *(_Float16*)&hb[0][lds_addr(row, col)] = (_Float16)c0[(16 * g + row) * Hh + col];
    }

    // Per-thread b128 voffsets into ys: (batch-row 16g+m, cols 32w+16tt+4q..+3).
    // The t term goes in soffset (t<<10).
    int voff[2];
#pragma unroll
    for (int tt = 0; tt < 2; ++tt)
        voff[tt] = (((16 * g + m) * Tt) * Hh + 32 * w + 16 * tt + 4 * q) * 4;

    // A-fragment LDS read addrs (row=m, col block 4c+q, swizzled), buffer 0.
    int ard[8];
#pragma unroll
    for (int c = 0; c < 8; ++c)
        ard[c] = m * 512 + ((((4 * c + q) ^ (m & 7)) & 31) << 4);

    // Packed h write addrs: (row m, cols 32w+16tt+4q..+3) -> one b64 per tile.
    // (col&7) = 4q&7 in {0,4} so the 4 f16 stay inside one swizzle block.
    int wadp[2];
#pragma unroll
    for (int tt = 0; tt < 2; ++tt)
        wadp[tt] = lds_addr(m, 32 * w + 16 * tt + 4 * q);

    // Prime px for t=0.
    floatx4 pxA[2], pxB[2];
#pragma unroll
    for (int tt = 0; tt < 2; ++tt) pxA[tt] = buf_load_f32x4(rsYS, voff[tt], 0);

    __syncthreads();

#define RNN_STEP(P, PXC, PXN, LASTCHK, TCUR)                                   \
    {                                                                          \
        /* A fragments first: MFMA needs them ASAP. */                         \
        half8 af[8];                                                           \
        _Pragma("unroll") for (int c2 = 0; c2 < 8; ++c2)                       \
            af[c2] = *(const half8*)&hb[(P)][ard[c2]];                         \
        /* Next step's px: issued now, consumed after the next barrier.        \
           At TCUR==Tt-1: last batch row goes OOB -> 0; others read garbage    \
           from the next row's region. Both unused. */                         \
        const int soffN = ((TCUR) + 1) << 10;                                  \
        PXN[0] = buf_load_f32x4(rsYS, voff[0], soffN);                         \
        PXN[1] = buf_load_f32x4(rsYS, voff[1], soffN);                         \
        floatx4 acc0 = PXC[0], acc1 = PXC[1];                                  \
        /* Swapped operands: D[col][row] -> lane (q,m): row m, cols 4q+r. */   \
        _Pragma("unroll") for (int c2 = 0; c2 < 8; ++c2)                       \
            acc0 = __builtin_amdgcn_mfma_f32_16x16x32_f16(bf[0][c2], af[c2],   \
                                                          acc0, 0, 0, 0);      \
        _Pragma("unroll") for (int c2 = 0; c2 < 8; ++c2)                       \
            acc1 = __builtin_amdgcn_mfma_f32_16x16x32_f16(bf[1][c2], af[c2],   \
                                                          acc1, 0, 0, 0);      \
        const int soffC = (TCUR) << 10;                                        \
        _Pragma("unroll") for (int u2 = 0; u2 < 2; ++u2) {                     \
            const floatx4 a2 = (u2 == 0) ? acc0 : acc1;                        \
            floatx4 hv;                                                        \
            _Pragma("unroll") for (int r2 = 0; r2 < 4; ++r2)                   \
                hv[r2] = fast_tanh(a2[r2]);                                    \
            buf_store_f32x4(hv, rsYS, voff[u2], soffC);                        \
            half4 hp;                                                          \
            _Pragma("unroll") for (int r2 = 0; r2 < 4; ++r2)                   \
                hp[r2] = (_Float16)hv[r2];                                     \
            *(half4*)&hb[(P) ^ 1][wadp[u2]] = hp;                              \
            if ((LASTCHK) && (TCUR) == Tt - 1)                                 \
                buf_store_f32x4(hv, rsHF,                                      \
                    ((16 * g + m) * Hh + 32 * w + 16 * u2 + 4 * q) * 4, 0);    \
        }                                                                      \
        LDS_BARRIER();                                                         \
    }

    for (int t = 0; t < Tt; t += 2) {
        RNN_STEP(0, pxA, pxB, 0, t)
        RNN_STEP(1, pxB, pxA, 1, t + 1)
    }
#undef RNN_STEP
}

extern "C" void kernel_launch(void* const* d_in, const int* in_sizes, int n_in,
                              void* d_out, int out_size, void* d_ws, size_t ws_size,
                              hipStream_t stream) {
    const float* c0  = (const float*)d_in[0];  // [B,H]
    const float* xs  = (const float*)d_in[1];  // [B,T,D]
    const float* Wih = (const float*)d_in[2];  // [D,H]
    const float* Whh = (const float*)d_in[3];  // [H,H]
    const float* bhh = (const float*)d_in[4];  // [H]
    float* out = (float*)d_out;
    float* hfin = out;                 // [B,H]
    float* ys = out + Bb * Hh;         // [B,T,H] — also holds px between kernels

    // 1024 blocks * 8 tiles * 16 rows = 131072 = B*T rows.
    px_gemm<<<1024, 256, 0, stream>>>(xs, Wih, bhh, ys);
    // 4 blocks * 16 rows = 64 batch chains.
    rnn_scan<<<Bb / 16, 512, 0, stream>>>(c0, Whh, hfin, ys);
}

// Round 6
// 1862.578 us; speedup vs baseline: 1.2149x; 1.2149x over previous
//
#include <hip/hip_runtime.h>

// Elman RNN on MI355X. B=64, T=2048, D=H=256.
// Kernel 1: px = xs @ W_ih + b_hh (swapped-operand f16 MFMA, b128 stores).
// Kernel 2: scan, 8 blocks x 8 batch rows (2x CUs vs before), 8 waves x 32
//           cols, 2 waves/SIMD. The 16-row MFMA A-operand is fed with rows
//           duplicated (lane m reads LDS row m&7 -> same-address broadcast,
//           free): halves per-CU LDS read bytes. Output rows 8-15 are dups;
//           lanes >=32 are masked off the epilogue (stores/tanh/LDS writes
//           halve). Flat pointers + hoisted byte offsets (r2 structure, the
//           measured best); LDS-only barrier (no vmcnt drain). ys overwritten
//           in place (px[b,t] read one step before h[b,t] written).

typedef _Float16 half8 __attribute__((ext_vector_type(8)));
typedef float floatx4 __attribute__((ext_vector_type(4)));
typedef float f32x4 __attribute__((ext_vector_type(4)));

constexpr int Bb = 64, Tt = 2048, Dd = 256, Hh = 256;

// LDS address for h[row][col], row in [0,8), col in [0,256), f16 elements.
// 16B blocks along col; XOR-swizzle block index with row so A-fragment
// ds_read_b128 (fixed col-block per lane, row=lane&7) is conflict-free and
// the 2B h-writes are 2-way (free tier).
__device__ __forceinline__ int lds_addr(int row, int col) {
    return row * 512 + ((((col >> 3) ^ (row & 7)) & 31) << 4) + ((col & 7) << 1);
}

__device__ __forceinline__ float fast_tanh(float x) {
    // tanh(x) = 1 - 2/(exp2(x*2*log2(e)) + 1); exact at +/-inf, ~1e-6 abs err.
    float e = __builtin_amdgcn_exp2f(x * 2.885390081777927f);
    float r = __builtin_amdgcn_rcpf(e + 1.0f);
    return __builtin_fmaf(-2.0f, r, 1.0f);
}

// LDS-only barrier: completes this wave's ds ops, then syncs. Does NOT drain
// vmcnt, so global loads/stores issued before it stay in flight across steps.
#define LDS_BARRIER() asm volatile("s_waitcnt lgkmcnt(0)\n\ts_barrier" ::: "memory")

// ---------------------------------------------------------------------------
// Kernel 1: px[b*T+t][n] = sum_k xs[b*T+t][k] * W_ih[k][n] + b_hh[n]
// Swapped-operand MFMA: lane holds (xs-row m, cols 64w+16tt+4q..+3) -> 4x b128
// stores per row-tile. (unchanged from round 5 — it passed and is ~260 us)
// ---------------------------------------------------------------------------
__global__ __launch_bounds__(256, 2) void px_gemm(const float* __restrict__ xs,
                                                  const float* __restrict__ Wih,
                                                  const float* __restrict__ bhh,
                                                  float* __restrict__ px) {
    const int lane = threadIdx.x & 63;
    const int w = threadIdx.x >> 6;   // 0..3
    const int q = lane >> 4;          // 0..3
    const int m = lane & 15;

    // W_ih fragments: lane (q,m) holds W[k=8q+j+32c][64w+16tt+m].
    half8 bf[4][8];
#pragma unroll
    for (int tt = 0; tt < 4; ++tt) {
        const int n = 64 * w + 16 * tt + m;
#pragma unroll
        for (int c = 0; c < 8; ++c) {
            half8 f;
#pragma unroll
            for (int j = 0; j < 8; ++j)
                f[j] = (_Float16)Wih[(32 * c + 8 * q + j) * Hh + n];
            bf[tt][c] = f;
        }
    }
    // Bias for the transposed output: cols 64w+16tt+4q..+3 (per-lane via q).
    f32x4 bias2[4];
#pragma unroll
    for (int tt = 0; tt < 4; ++tt)
        bias2[tt] = *(const f32x4*)(bhh + 64 * w + 16 * tt + 4 * q);

    for (int i = 0; i < 8; ++i) {
        const int tau = blockIdx.x * 8 + i;             // 16-row tile index
        const float* arow = xs + (size_t)(tau * 16 + m) * Dd;
        half8 af[8];
#pragma unroll
        for (int c = 0; c < 8; ++c) {
            f32x4 lo = *(const f32x4*)(arow + 32 * c + 8 * q);
            f32x4 hi = *(const f32x4*)(arow + 32 * c + 8 * q + 4);
            half8 f;
            f[0] = (_Float16)lo[0]; f[1] = (_Float16)lo[1];
            f[2] = (_Float16)lo[2]; f[3] = (_Float16)lo[3];
            f[4] = (_Float16)hi[0]; f[5] = (_Float16)hi[1];
            f[6] = (_Float16)hi[2]; f[7] = (_Float16)hi[3];
            af[c] = f;
        }
        floatx4 acc[4];
#pragma unroll
        for (int tt = 0; tt < 4; ++tt) {
            acc[tt][0] = bias2[tt][0]; acc[tt][1] = bias2[tt][1];
            acc[tt][2] = bias2[tt][2]; acc[tt][3] = bias2[tt][3];
        }
        // Swapped operands: D[wih-col][xs-row] -> lane (q,m): row m, cols 4q+r.
#pragma unroll
        for (int c = 0; c < 8; ++c)
#pragma unroll
            for (int tt = 0; tt < 4; ++tt)
                acc[tt] = __builtin_amdgcn_mfma_f32_16x16x32_f16(bf[tt][c], af[c], acc[tt], 0, 0, 0);
#pragma unroll
        for (int tt = 0; tt < 4; ++tt)
            *(f32x4*)(px + (size_t)(tau * 16 + m) * Hh + 64 * w + 16 * tt + 4 * q) =
                *(f32x4*)&acc[tt];
    }
}

// ---------------------------------------------------------------------------
// Kernel 2: scan. Grid = 8 blocks (8 batch rows each), 512 thr = 8 waves
// (2 waves/SIMD). Wave w owns cols [32w, 32w+32); W_hh fragments in 64 VGPRs.
// A-fragment rows duplicated: lane m reads LDS row m&7 (broadcast). Output
// rows 4q+r for q>=2 are dups of q-2 -> epilogue masked to lane<32.
// Per step: 8x ds_read_b128 (512B unique each), 8x b32 px prefetch (dup rows,
// rides across the barrier), 16 MFMA, masked tanh + b32 ys store + b16 LDS
// h-write, LDS-only barrier.
// ---------------------------------------------------------------------------
__global__ __launch_bounds__(512, 2) void rnn_scan(const float* __restrict__ c0,
                                                   const float* __restrict__ Whh,
                                                   float* __restrict__ hfin,
                                                   float* __restrict__ ys) {
    __shared__ alignas(16) unsigned char hb[2][4096];
    const int g = blockIdx.x;         // row group: rows [8g, 8g+8)
    const int lane = threadIdx.x & 63;
    const int w = threadIdx.x >> 6;   // 0..7
    const int q = lane >> 4;
    const int m = lane & 15;

    // W_hh B fragments (one-time, scattered fp32 loads + cvt). 64 VGPRs.
    half8 bf[2][8];
#pragma unroll
    for (int tt = 0; tt < 2; ++tt) {
        const int n = 32 * w + 16 * tt + m;
#pragma unroll
        for (int c = 0; c < 8; ++c) {
            half8 f;
#pragma unroll
            for (int j = 0; j < 8; ++j)
                f[j] = (_Float16)Whh[(32 * c + 8 * q + j) * Hh + n];
            bf[tt][c] = f;
        }
    }

    // h_0 = c rows -> LDS buffer 0 (f16, swizzled). 8 rows.
    for (int i = threadIdx.x; i < 8 * 256; i += 512) {
        const int row = i >> 8, col = i & 255;
        *(_Float16*)&hb[0][lds_addr(row, col)] = (_Float16)c0[(8 * g + row) * Hh + col];
    }

    // Per-thread byte offsets into ys (row-major [B,T,H]; t term added via
    // uniform base pointers). Rows dup'd via &7 so q>=2 lanes load valid
    // (unused) addresses. k = 4*tt + r. Max 128 MB, fits unsigned.
    unsigned boff[8];
#pragma unroll
    for (int tt = 0; tt < 2; ++tt)
#pragma unroll
        for (int r = 0; r < 4; ++r)
            boff[4 * tt + r] =
                (unsigned)(((8 * g + ((4 * q + r) & 7)) * Tt) * Hh + 32 * w + 16 * tt + m) * 4u;

    // A-fragment LDS read addrs (row=m&7 dup-broadcast, col block 4c+q, swizzled).
    int ard[8];
#pragma unroll
    for (int c = 0; c < 8; ++c)
        ard[c] = (m & 7) * 512 + ((((4 * c + q) ^ (m & 7)) & 31) << 4);

    // h write LDS addrs (used only by lane<32, rows 4q+r in [0,8)).
    int wad[8];
#pragma unroll
    for (int tt = 0; tt < 2; ++tt)
#pragma unroll
        for (int r = 0; r < 4; ++r)
            wad[4 * tt + r] = lds_addr((4 * q + r) & 7, 32 * w + 16 * tt + m);

    const char* pxp = (const char*)ys;                              // prefetch base
    const char* pxlast = (const char*)ys + (size_t)(Tt - 1) * Hh * 4;
    char* yst = (char*)ys;                                          // store base

    // Prime px for t=0.
    float pxA[8], pxB[8];
#pragma unroll
    for (int k = 0; k < 8; ++k) pxA[k] = *(const float*)(pxp + boff[k]);
    pxp += Hh * 4;

    __syncthreads();

#define RNN_STEP(P, PXC, PXN, LASTCHK, TCUR)                                   \
    {                                                                          \
        /* A fragments first: MFMA needs them ASAP. */                         \
        half8 af[8];                                                           \
        _Pragma("unroll") for (int c2 = 0; c2 < 8; ++c2)                       \
            af[c2] = *(const half8*)&hb[(P)][ard[c2]];                         \
        /* Next step's px: issued now, consumed after the next barrier. */     \
        const char* pf = (pxp > pxlast) ? pxlast : pxp; /* uniform clamp */    \
        _Pragma("unroll") for (int k2 = 0; k2 < 8; ++k2)                       \
            PXN[k2] = *(const float*)(pf + boff[k2]);                          \
        pxp += Hh * 4;                                                         \
        floatx4 acc0, acc1;                                                    \
        _Pragma("unroll") for (int i2 = 0; i2 < 4; ++i2) {                     \
            acc0[i2] = PXC[i2]; acc1[i2] = PXC[4 + i2];                        \
        }                                                                      \
        _Pragma("unroll") for (int c2 = 0; c2 < 8; ++c2)                       \
            acc0 = __builtin_amdgcn_mfma_f32_16x16x32_f16(af[c2], bf[0][c2],   \
                                                          acc0, 0, 0, 0);      \
        _Pragma("unroll") for (int c2 = 0; c2 < 8; ++c2)                       \
            acc1 = __builtin_amdgcn_mfma_f32_16x16x32_f16(af[c2], bf[1][c2],   \
                                                          acc1, 0, 0, 0);      \
        if (lane < 32) { /* lanes holding unique output rows */                \
            _Pragma("unroll") for (int r2 = 0; r2 < 4; ++r2) {                 \
                const float hv = fast_tanh(acc0[r2]);                          \
                *(float*)(yst + boff[r2]) = hv;                                \
                *(_Float16*)&hb[(P) ^ 1][wad[r2]] = (_Float16)hv;              \
                if ((LASTCHK) && (TCUR) == Tt - 1)                             \
                    hfin[(8 * g + 4 * q + r2) * Hh + 32 * w + m] = hv;         \
            }                                                                  \
            _Pragma("unroll") for (int r2 = 0; r2 < 4; ++r2) {                 \
                const float hv = fast_tanh(acc1[r2]);                          \
                *(float*)(yst + boff[4 + r2]) = hv;                            \
                *(_Float16*)&hb[(P) ^ 1][wad[4 + r2]] = (_Float16)hv;          \
                if ((LASTCHK) && (TCUR) == Tt - 1)                             \
                    hfin[(8 * g + 4 * q + r2) * Hh + 32 * w + 16 + m] = hv;    \
            }                                                                  \
        }                                                                      \
        yst += Hh * 4;                                                         \
        LDS_BARRIER();                                                         \
    }

    for (int t = 0; t < Tt; t += 2) {
        RNN_STEP(0, pxA, pxB, 0, t)
        RNN_STEP(1, pxB, pxA, 1, t + 1)
    }
#undef RNN_STEP
}

extern "C" void kernel_launch(void* const* d_in, const int* in_sizes, int n_in,
                              void* d_out, int out_size, void* d_ws, size_t ws_size,
                              hipStream_t stream) {
    const float* c0  = (const float*)d_in[0];  // [B,H]
    const float* xs  = (const float*)d_in[1];  // [B,T,D]
    const float* Wih = (const float*)d_in[2];  // [D,H]
    const float* Whh = (const float*)d_in[3];  // [H,H]
    const float* bhh = (const float*)d_in[4];  // [H]
    float* out = (float*)d_out;
    float* hfin = out;                 // [B,H]
    float* ys = out + Bb * Hh;         // [B,T,H] — also holds px between kernels

    // 1024 blocks * 8 tiles * 16 rows = 131072 = B*T rows.
    px_gemm<<<1024, 256, 0, stream>>>(xs, Wih, bhh, ys);
    // 8 blocks * 8 rows = 64 batch chains.
    rnn_scan<<<Bb / 8, 512, 0, stream>>>(c0, Whh, hfin, ys);
}